// Round 8
// baseline (279.797 us; speedup 1.0000x reference)
//
#include <hip/hip_runtime.h>

#define B 256
#define T 2048
#define L 48
#define G 16           // segments per batch chain
#define SEG 128        // steps per segment (last: 127)
#define KNORM 4.371f   // per-step constant renorm: ln(48*e^0.5)
#define TOTALF (B * T * L)

typedef short v4s __attribute__((ext_vector_type(4)));
typedef short v8s __attribute__((ext_vector_type(8)));
typedef float v4f __attribute__((ext_vector_type(4)));
typedef float v2f __attribute__((ext_vector_type(2)));
typedef int   v2i __attribute__((ext_vector_type(2)));
typedef int   v4i __attribute__((ext_vector_type(4)));

// Single-wave "barrier" (combine kernel only): drain LDS counters, not vmcnt.
#define WAVE_SYNC() asm volatile("s_waitcnt lgkmcnt(0)" ::: "memory")

#if __has_builtin(__builtin_amdgcn_mfma_f32_16x16x16bf16_1k)
#define MFMA16(a, b, c) __builtin_amdgcn_mfma_f32_16x16x16bf16_1k((a), (b), (c), 0, 0, 0)
#else
__device__ __forceinline__ v4f mfma16_asm(v4s a, v4s b, v4f c) {
    asm volatile("v_mfma_f32_16x16x16_bf16 %0, %1, %2, %0\n\ts_nop 7\n\ts_nop 7"
                 : "+v"(c) : "v"(a), "v"(b));
    return c;
}
#define MFMA16(a, b, c) mfma16_asm((a), (b), (c))
#endif

#if __has_builtin(__builtin_amdgcn_mfma_f32_16x16x32_bf16)
#define MFMA32(a, b, c) __builtin_amdgcn_mfma_f32_16x16x32_bf16((a), (b), (c), 0, 0, 0)
#else
__device__ __forceinline__ v4f mfma32_asm(v8s a, v8s b, v4f c) {
    asm volatile("v_mfma_f32_16x16x32_bf16 %0, %1, %2, %0\n\ts_nop 7\n\ts_nop 7"
                 : "+v"(c) : "v"(a), "v"(b));
    return c;
}
#define MFMA32(a, b, c) mfma32_asm((a), (b), (c))
#endif

// pack two fp32 -> (bf16(hi)<<16)|bf16(lo)
__device__ __forceinline__ unsigned pk_bf16(float lo, float hi) {
#if __has_builtin(__builtin_amdgcn_cvt_pk_bf16_f32)
    auto r = __builtin_amdgcn_cvt_pk_bf16_f32(lo, hi);   // HW RNE pack (gfx950)
    unsigned u;
    __builtin_memcpy(&u, &r, 4);
    return u;
#else
    unsigned uh = __float_as_uint(hi) + 0x8000u;         // round-half-up
    unsigned ul = __float_as_uint(lo) + 0x8000u;
    return __builtin_amdgcn_perm(uh, ul, 0x07060302u);
#endif
}

// ---------------------------------------------------------------------------
// Segment scan, column-split, K-fused: workgroup (b,s) = 3 waves; wave ct owns
// a 16-column slice of Q_s = prod_t [D(g_t) E^T / e^K].  Per step per wave:
// each output row-tile rt does K=48 as ONE 16x16x32 (k-tiles 0,1) plus ONE
// 16x16x16 (k-tile 2)  ->  6 MFMA/wave-step (was 9).
// K=32 trick: B slot (q,j) carries C0.reg[j] (row 4q+j) for j<4 and
// C1.reg[j-4] (row 16+4q+j-4) for j>=4; the SAME slot->row permutation is
// baked into the constant A fragments (E^T), so A.k pairs with B.k correctly
// with zero runtime shuffles.  C/D layout == K16 B layout handles k-tile 2.
// g = exp(em - K) staged in LDS once per workgroup (double-buffered).
// ---------------------------------------------------------------------------
__global__ __launch_bounds__(192, 6) void crf_scan(
    const float* __restrict__ em, const int* __restrict__ tags,
    const float* __restrict__ trans, float* __restrict__ out,
    float* __restrict__ ws)
{
    const int b   = blockIdx.x >> 4;
    const int s   = blockIdx.x & 15;
    const int tid = threadIdx.x;
    const int ct  = tid >> 6;          // wave = column tile 0..2
    const int ln  = tid & 63;
    const int q   = ln >> 4;           // 0..3
    const int c   = ln & 15;           // 0..15
    const int col = 16 * ct + c;       // owned Q column

    __shared__ __align__(16) float smem[2 * 384];   // 8 g-rows x 2 buffers

    const size_t bem = (size_t)b * T * L;
    const int t0 = 1 + SEG * s;
    const int t1 = (t0 + SEG < T) ? (t0 + SEG) : T;   // s=15 -> 127 steps

    // --- constant A fragments of E^T, with the custom k-permutation -------
    // A32[rt] slot (q,j): k_row = (j<4) ? 4q+j : 16+4q+(j-4); m = 16rt+c.
    // A16[rt] slot (q,e): k_row = 32+4q+e.
    v8s A32[3];
    v4s A16[3];
    #pragma unroll
    for (int rt = 0; rt < 3; ++rt) {
        v4f e0, e1, e2;
        #pragma unroll
        for (int jj = 0; jj < 4; ++jj) {
            e0[jj] = __expf(trans[(     4 * q + jj) * L + 16 * rt + c]);
            e1[jj] = __expf(trans[(16 + 4 * q + jj) * L + 16 * rt + c]);
            e2[jj] = __expf(trans[(32 + 4 * q + jj) * L + 16 * rt + c]);
        }
        v4i d;
        d.x = (int)pk_bf16(e0.x, e0.y);
        d.y = (int)pk_bf16(e0.z, e0.w);
        d.z = (int)pk_bf16(e1.x, e1.y);
        d.w = (int)pk_bf16(e1.z, e1.w);
        A32[rt] = __builtin_bit_cast(v8s, d);
        v2i d2;
        d2.x = (int)pk_bf16(e2.x, e2.y);
        d2.y = (int)pk_bf16(e2.z, e2.w);
        A16[rt] = __builtin_bit_cast(v4s, d2);
    }

    // --- state slice as B fragments, init = identity columns --------------
    v8s B32;   // rows 0..31 (k-tiles 0,1), permuted slot order
    v4s B16;   // rows 32..47
    {
        v4i d;
        d.x = (int)(( 4*q+0 == col ? 0x3F80u : 0u) | ( 4*q+1 == col ? 0x3F800000u : 0u));
        d.y = (int)(( 4*q+2 == col ? 0x3F80u : 0u) | ( 4*q+3 == col ? 0x3F800000u : 0u));
        d.z = (int)((16+4*q+0 == col ? 0x3F80u : 0u) | (16+4*q+1 == col ? 0x3F800000u : 0u));
        d.w = (int)((16+4*q+2 == col ? 0x3F80u : 0u) | (16+4*q+3 == col ? 0x3F800000u : 0u));
        B32 = __builtin_bit_cast(v8s, d);
        v2i d2;
        d2.x = (int)((32+4*q+0 == col ? 0x3F80u : 0u) | (32+4*q+1 == col ? 0x3F800000u : 0u));
        d2.y = (int)((32+4*q+2 == col ? 0x3F80u : 0u) | (32+4*q+3 == col ? 0x3F800000u : 0u));
        B16 = __builtin_bit_cast(v4s, d2);
    }

    auto do_step = [&](const float* rowp) {
        v4f g0 = *(const v4f*)(rowp +      4 * q);
        v4f g1 = *(const v4f*)(rowp + 16 + 4 * q);
        v4f g2 = *(const v4f*)(rowp + 32 + 4 * q);
        v4f C0, C1, C2;
        {
            v4f a = {0.f, 0.f, 0.f, 0.f};
            a = MFMA32(A32[0], B32, a);
            a = MFMA16(A16[0], B16, a);
            C0 = a;
        }
        {
            v4f a = {0.f, 0.f, 0.f, 0.f};
            a = MFMA32(A32[1], B32, a);
            a = MFMA16(A16[1], B16, a);
            C1 = a;
        }
        {
            v4f a = {0.f, 0.f, 0.f, 0.f};
            a = MFMA32(A32[2], B32, a);
            a = MFMA16(A16[2], B16, a);
            C2 = a;
        }
        // row-scale by g (paired muls -> v_pk_mul_f32) and pack to bf16
        v2f p0 = v2f{C0.x, C0.y} * v2f{g0.x, g0.y};
        v2f p1 = v2f{C0.z, C0.w} * v2f{g0.z, g0.w};
        v2f p2 = v2f{C1.x, C1.y} * v2f{g1.x, g1.y};
        v2f p3 = v2f{C1.z, C1.w} * v2f{g1.z, g1.w};
        v2f p4 = v2f{C2.x, C2.y} * v2f{g2.x, g2.y};
        v2f p5 = v2f{C2.z, C2.w} * v2f{g2.z, g2.w};
        v4i nb;
        nb.x = (int)pk_bf16(p0.x, p0.y);
        nb.y = (int)pk_bf16(p1.x, p1.y);
        nb.z = (int)pk_bf16(p2.x, p2.y);
        nb.w = (int)pk_bf16(p3.x, p3.y);
        B32 = __builtin_bit_cast(v8s, nb);
        v2i nb2;
        nb2.x = (int)pk_bf16(p4.x, p4.y);
        nb2.y = (int)pk_bf16(p5.x, p5.y);
        B16 = __builtin_bit_cast(v4s, nb2);
    };

    // stage g-rows t0..t0+7 into buffer 0 (cooperative: 2 floats/lane)
    {
        size_t gf = bem + (size_t)t0 * L;
        smem[tid]       = __expf(em[gf + tid]       - KNORM);
        smem[tid + 192] = __expf(em[gf + tid + 192] - KNORM);
        __syncthreads();
    }

    for (int bk = 0; bk < 16; ++bk) {
        const float* cur = smem + (bk & 1) * 384;
        float* nxt = smem + ((bk & 1) ^ 1) * 384;

        size_t gf = bem + (size_t)(t0 + 8 * (bk + 1)) * L;
        if (gf > (size_t)TOTALF - 384) gf = (size_t)TOTALF - 384;
        float stg0 = em[gf + tid];
        float stg1 = em[gf + tid + 192];

        #pragma unroll
        for (int k = 0; k < 8; ++k)
            if (t0 + 8 * bk + k < t1)            // workgroup-uniform guard
                do_step(cur + 48 * k);

        nxt[tid]       = __expf(stg0 - KNORM);
        nxt[tid + 192] = __expf(stg1 - KNORM);
        __syncthreads();
    }

    // store this wave's 16-col slice of Q, bf16 row-major [row*48+col]
    unsigned short* qs = (unsigned short*)ws + (size_t)(b * G + s) * 2304;
    #pragma unroll
    for (int jj = 0; jj < 8; ++jj) {
        int row = (jj < 4) ? (4 * q + jj) : (16 + 4 * q + jj - 4);
        qs[row * 48 + col] = (unsigned short)B32[jj];
    }
    #pragma unroll
    for (int r = 0; r < 4; ++r)
        qs[(32 + 4 * q + r) * 48 + col] = (unsigned short)B16[r];

    // fused gold score for t in [128 s, 128 s + 128): one t per lane, tid<128
    const int* tg = tags + (size_t)b * T;
    float gp = 0.f;
    if (tid < 128) {
        int t = SEG * s + tid;
        int tag = tg[t];
        gp += em[bem + (size_t)t * L + tag];
        if (t < T - 1)  gp += trans[tag * L + tg[t + 1]];
        if (t == 0)     gp += trans[tag];
        if (t == T - 1) gp += trans[tag * L + (L - 1)];
    }
    #pragma unroll
    for (int off = 32; off; off >>= 1) gp += __shfl_xor(gp, off);
    __shared__ float red[3];
    if (ln == 0) red[ct] = gp;
    __syncthreads();
    if (tid == 0) atomicAdd(out, -(red[0] + red[1] + red[2]));
}

// ---------------------------------------------------------------------------
// Combine: per batch, u = alpha_0; for s: u = Q_s u (renormed, bf16 rows,
// next-segment register prefetch); Z_b = log(sum u_i E[i][end]) + 2047*K +
// accumulated renorm logs.  Lane l owns row l => no cross-lane reduce.
// ---------------------------------------------------------------------------
__global__ __launch_bounds__(64) void crf_combine(
    const float* __restrict__ em, const float* __restrict__ trans,
    const float* __restrict__ ws, float* __restrict__ out)
{
    const int b = blockIdx.x, l = threadIdx.x;
    const int lc = (l < L) ? l : (L - 1);

    __shared__ float us[64];

    const unsigned short* qb = (const unsigned short*)ws + (size_t)b * G * 2304;

    float u = (l < L) ? __expf(trans[l] + em[(size_t)b * T * L + l]) : 0.f;
    float logtot = 2047.0f * KNORM;

    uint4 pre[6];
    {
        const uint4* p = (const uint4*)(qb + lc * 48);
        #pragma unroll
        for (int ii = 0; ii < 6; ++ii) pre[ii] = p[ii];
    }

    for (int s = 0; s < G; ++s) {
        us[l] = u;
        uint4 cur[6];
        #pragma unroll
        for (int ii = 0; ii < 6; ++ii) cur[ii] = pre[ii];
        if (s + 1 < G) {
            const uint4* p = (const uint4*)(qb + (size_t)(s + 1) * 2304 + lc * 48);
            #pragma unroll
            for (int ii = 0; ii < 6; ++ii) pre[ii] = p[ii];
        }
        WAVE_SYNC();

        float acc = 0.f;
        #pragma unroll
        for (int ii = 0; ii < 6; ++ii) {
            unsigned w0 = cur[ii].x, w1 = cur[ii].y, w2 = cur[ii].z, w3 = cur[ii].w;
            int jj = ii * 8;
            acc = fmaf(__uint_as_float(w0 << 16),          us[jj + 0], acc);
            acc = fmaf(__uint_as_float(w0 & 0xffff0000u),  us[jj + 1], acc);
            acc = fmaf(__uint_as_float(w1 << 16),          us[jj + 2], acc);
            acc = fmaf(__uint_as_float(w1 & 0xffff0000u),  us[jj + 3], acc);
            acc = fmaf(__uint_as_float(w2 << 16),          us[jj + 4], acc);
            acc = fmaf(__uint_as_float(w2 & 0xffff0000u),  us[jj + 5], acc);
            acc = fmaf(__uint_as_float(w3 << 16),          us[jj + 6], acc);
            acc = fmaf(__uint_as_float(w3 & 0xffff0000u),  us[jj + 7], acc);
        }
        WAVE_SYNC();   // us reads done before next overwrite

        float r = __int_as_float(
            __builtin_amdgcn_readlane(__float_as_int(acc), 0));
        logtot += __logf(r);
        u = (l < L) ? acc * __builtin_amdgcn_rcpf(r) : 0.f;
    }

    float v = (l < L) ? u * __expf(trans[lc * L + (L - 1)]) : 0.f;
    #pragma unroll
    for (int off = 32; off; off >>= 1) v += __shfl_xor(v, off);
    if (l == 0) atomicAdd(out, logtot + __logf(v));
}

extern "C" void kernel_launch(void* const* d_in, const int* in_sizes, int n_in,
                              void* d_out, int out_size, void* d_ws, size_t ws_size,
                              hipStream_t stream) {
    const float* em    = (const float*)d_in[0];   // (B, T, L) f32
    const int*   tags  = (const int*)  d_in[1];   // (B, T) i32
    const float* trans = (const float*)d_in[2];   // (L, L) f32
    float* out = (float*)d_out;
    float* ws  = (float*)d_ws;                    // 4096 * 2304 bf16 = 18.9 MB

    (void)hipMemsetAsync(out, 0, sizeof(float), stream);
    crf_scan   <<<B * G, 192, 0, stream>>>(em, tags, trans, out, ws);
    crf_combine<<<B,      64, 0, stream>>>(em, trans, ws, out);
}